// Round 11
// baseline (41.155 us; speedup 1.0000x reference)
//
#include <hip/hip_runtime.h>

#define EPSF 1e-8f
#define R2C  0.0025f   // 0.05^2
#define NJ   32        // j-chunks (grid.y of K1)

// ---------------- ws float-index layout ----------------
// wsu[0]                 : ticket for k_final (ACCUMULATING across launches;
//                          "prev % grid == grid-1" fires exactly once per
//                          launch for any start value -> no reset needed)
// ws[64 + sl*16 + 0..12] : K1 prep rows (sl < nsl=16):
//                          {hx,hy,hz,nh,pv,gv,nb,hxx,hxy,hxz,hyy,hyz,hzz}
// ws[1024 + blk*16+0..4] : K2 rows {sd, sd2, maxd, sv, nv} (atomic publish/read)
// ws[4096 + ...]         : pair partials cnt[NJ][n], sx[NJ][n], sx2[NJ][n]
//                          (written ONLY for boundary i; k_final reads gated by b)
// total ~3.2 MB << ws_size.

__device__ inline int read_mask(const void* p, int i, int isInt) {
    if (isInt) return ((const int*)p)[i] != 0;
    return ((const unsigned char*)p)[i] != 0;
}
__device__ inline float wave_sum(float v) {
    #pragma unroll
    for (int o = 32; o > 0; o >>= 1) v += __shfl_down(v, o, 64);
    return v;
}
__device__ inline float wave_max(float v) {
    #pragma unroll
    for (int o = 32; o > 0; o >>= 1) v = fmaxf(v, __shfl_down(v, o, 64));
    return v;
}

// K1: pair sweep with BOTH-side boundary compaction (i and j), since
// vf = neighborhood * bf_i * bf_j. grid (nsl, NJ). 512-row i-slab/block,
// 2 raw rows/thread; compacted ~50% into LDS. c==0 plane emits 13-wide
// moment rows over ALL points (pre-compaction).
__global__ __launch_bounds__(256, 4)
void k_pairs(const float* __restrict__ pts, const float* __restrict__ segp,
             const void* bm, const void* hm, const void* pm, const void* gm,
             float* __restrict__ ws, int n, int nbi) {
    __shared__ float4 t4[256];     // compacted j: {-2x,-2y,-2z, sq}
    __shared__ float2 tv[256];     // compacted j: {v, v^2}
    __shared__ float4 ci4[512];    // compacted i: {x, y, z, thr}
    __shared__ short  ilist[512];  // compacted i -> local row (0..511)
    __shared__ int bad[4];
    __shared__ int wcj[4];         // j-compaction per-wave counts
    __shared__ int wci[8];         // i-compaction counts: set0 w0..3, set1 w0..3
    __shared__ float pacc[13];
    int tid = threadIdx.x, lane = tid & 63, wv = tid >> 6;
    int bx = blockIdx.x, c = blockIdx.y;

    if (tid < 4) { bad[tid] = 0; wcj[tid] = 0; }
    if (tid < 8) wci[tid] = 0;
    if (tid < 13) pacc[tid] = 0.f;
    __syncthreads();
    {   // mask layout detect: byte layout shows nonzero upper bytes in the
        // first 256 words unless the first 1024 bools are all false (p~2^-768)
        unsigned w0 = ((const unsigned*)bm)[tid & 255];
        if (w0 & 0xFFFFFF00u) atomicOr(&bad[0], 1);
        if (c == 0) {
            unsigned w1 = ((const unsigned*)hm)[tid & 255];
            unsigned w2 = ((const unsigned*)pm)[tid & 255];
            unsigned w3 = ((const unsigned*)gm)[tid & 255];
            if (w1 & 0xFFFFFF00u) atomicOr(&bad[1], 1);
            if (w2 & 0xFFFFFF00u) atomicOr(&bad[2], 1);
            if (w3 & 0xFFFFFF00u) atomicOr(&bad[3], 1);
        }
    }
    __syncthreads();

    // ---- two raw i-rows per thread ----
    int i0 = bx*512 + tid, i1 = i0 + 256;
    int ic0 = min(i0, n-1), ic1 = min(i1, n-1);
    bool a0 = i0 < n, a1 = i1 < n;
    float x0 = pts[3*ic0], y0 = pts[3*ic0+1], z0 = pts[3*ic0+2];
    float x1 = pts[3*ic1], y1 = pts[3*ic1+1], z1 = pts[3*ic1+2];
    bool b0 = read_mask(bm, ic0, !bad[0]) && a0;
    bool b1 = read_mask(bm, ic1, !bad[0]) && a1;

    if (c == 0) {   // prep rows: counts + first AND raw second head moments
        int h0 = read_mask(hm, ic0, !bad[1]) && a0;
        int h1 = read_mask(hm, ic1, !bad[1]) && a1;
        int p0 = read_mask(pm, ic0, !bad[2]) && a0;
        int p1 = read_mask(pm, ic1, !bad[2]) && a1;
        int g0 = read_mask(gm, ic0, !bad[3]) && a0;
        int g1 = read_mask(gm, ic1, !bad[3]) && a1;
        float hf0 = h0 ? 1.f : 0.f, hf1 = h1 ? 1.f : 0.f;
        float vals[13] = {
            hf0*x0 + hf1*x1, hf0*y0 + hf1*y1, hf0*z0 + hf1*z1,
            hf0 + hf1, (float)(p0 + p1), (float)(g0 + g1),
            (float)((int)b0 + (int)b1),
            hf0*x0*x0 + hf1*x1*x1, hf0*x0*y0 + hf1*x1*y1, hf0*x0*z0 + hf1*x1*z1,
            hf0*y0*y0 + hf1*y1*y1, hf0*y0*z0 + hf1*y1*z1, hf0*z0*z0 + hf1*z1*z1 };
        #pragma unroll
        for (int k = 0; k < 13; ++k) {
            float s = wave_sum(vals[k]);
            if (lane == 0) atomicAdd(&pacc[k], s);   // LDS atomic: on-CU, cheap
        }
        __syncthreads();
        if (tid < 13) ws[64 + bx*16 + tid] = pacc[tid];
    }

    // ---- i-compaction (deterministic: set-major, wave-major, lane-minor) ----
    {
        unsigned long long ball0 = __ballot(b0);
        unsigned long long ball1 = __ballot(b1);
        if (lane == 0) { wci[wv] = __popcll(ball0); wci[4 + wv] = __popcll(ball1); }
        __syncthreads();
        unsigned long long lmask = (1ull << lane) - 1ull;
        int base0 = 0, base1 = wci[0] + wci[1] + wci[2] + wci[3];
        #pragma unroll
        for (int w = 0; w < 4; ++w) {
            base0 += (w < wv) ? wci[w] : 0;
            base1 += (w < wv) ? wci[4 + w] : 0;
        }
        if (b0) {
            int e = base0 + __popcll(ball0 & lmask);
            ci4[e] = make_float4(x0, y0, z0, R2C - (x0*x0 + y0*y0 + z0*z0));
            ilist[e] = (short)tid;
        }
        if (b1) {
            int e = base1 + __popcll(ball1 & lmask);
            ci4[e] = make_float4(x1, y1, z1, R2C - (x1*x1 + y1*y1 + z1*z1));
            ilist[e] = (short)(tid + 256);
        }
    }

    // ---- j-tile staging with boundary compaction (tile t = c) ----
    {
        int j = c*256 + tid;
        int jc = min(j, n-1);
        bool jb = (j < n) && read_mask(bm, jc, !bad[0]);
        float xj = pts[3*jc], yj = pts[3*jc+1], zj = pts[3*jc+2];
        float v = segp[3*jc+2];
        float sqj = xj*xj + yj*yj + zj*zj;
        unsigned long long ball = __ballot(jb);
        int pre = __popcll(ball & ((1ull << lane) - 1ull));
        if (lane == 0) wcj[wv] = __popcll(ball);
        __syncthreads();
        int base = 0;
        #pragma unroll
        for (int w = 0; w < 4; ++w) base += (w < wv) ? wcj[w] : 0;
        if (jb) {
            int r = base + pre;
            t4[r] = make_float4(-2.f*xj, -2.f*yj, -2.f*zj, sqj);
            tv[r] = make_float2(v, v*v);
        }
    }
    __syncthreads();
    int JC   = wcj[0] + wcj[1] + wcj[2] + wcj[3];
    int icnt = wci[0] + wci[1] + wci[2] + wci[3]
             + wci[4] + wci[5] + wci[6] + wci[7];

    float* __restrict__ outb = ws + 4096;
    for (int e = tid; e < icnt; e += 256) {
        float4 ci = ci4[e];
        float cc = 0.f, s1 = 0.f, s2 = 0.f;
        #pragma unroll 4
        for (int k = 0; k < JC; ++k) {
            float4 pj = t4[k];
            float2 vv = tv[k];
            float t = fmaf(pj.x, ci.x, pj.w);
            t = fmaf(pj.y, ci.y, t);
            t = fmaf(pj.z, ci.z, t);
            float m = (t < ci.w) ? 1.f : 0.f;
            cc += m;
            s1 = fmaf(m, vv.x, s1);
            s2 = fmaf(m, vv.y, s2);
        }
        int i = bx*512 + (int)ilist[e];
        outb[(size_t)c*n + i]          = cc;
        outb[(size_t)(NJ + c)*n + i]   = s1;
        outb[(size_t)(2*NJ + c)*n + i] = s2;
    }
}

// K2: conn reductions + gated partial reduce + last-block assembly.
__global__ void k_final(const float* __restrict__ pts, const void* bm, const void* hm,
                        float* __restrict__ ws, float* __restrict__ out,
                        int n, int nbi, int nsl) {
    __shared__ int badb, badh, lastf, bmax;
    __shared__ float ctr[13];
    __shared__ float bacc[4];    // {sd, sd2, sv, nv}
    int tid = threadIdx.x, lane = tid & 63;
    if (tid == 0) { badb = 0; badh = 0; lastf = 0; bmax = 0; }
    if (tid < 4) bacc[tid] = 0.f;
    __syncthreads();
    unsigned wb = ((const unsigned*)bm)[tid & 255];
    unsigned wh = ((const unsigned*)hm)[tid & 255];
    if (wb & 0xFFFFFF00u) atomicOr(&badb, 1);
    if (wh & 0xFFFFFF00u) atomicOr(&badh, 1);

    // sum prep rows (nsl <= 64) -> counts, centroid, raw moments
    if (tid < 64) {
        float s[13] = {0,0,0,0,0,0,0,0,0,0,0,0,0};
        for (int r = tid; r < nsl; r += 64) {
            #pragma unroll
            for (int k = 0; k < 13; ++k) s[k] += ws[64 + r*16 + k];
        }
        #pragma unroll
        for (int k = 0; k < 13; ++k) {
            #pragma unroll
            for (int o = 32; o > 0; o >>= 1) s[k] += __shfl_down(s[k], o, 64);
        }
        if (tid == 0) {
            #pragma unroll
            for (int k = 0; k < 13; ++k) ctr[k] = s[k];
        }
    }
    __syncthreads();

    float nh = ctr[3];
    float inv = (nh > 0.f) ? 1.f/nh : 0.f;
    float cx = ctr[0]*inv, cy = ctr[1]*inv, cz = ctr[2]*inv;
    int i = blockIdx.x*256 + tid;
    int ic = min(i, n-1);
    float act = (i < n) ? 1.f : 0.f;
    float x = pts[3*ic], y = pts[3*ic+1], z = pts[3*ic+2];
    int h = read_mask(hm, ic, !badh);
    float m = (h ? 1.f : 0.f) * act;
    float dx = x-cx, dy = y-cy, dz = z-cz;
    float d = sqrtf(dx*dx + dy*dy + dz*dz);
    {
        float s0 = wave_sum(m*d);
        float s1 = wave_sum(m*d*d);
        float dm = wave_max(m > 0.f ? d : 0.f);
        if (lane == 0) {
            atomicAdd(&bacc[0], s0); atomicAdd(&bacc[1], s1);
            atomicMax(&bmax, __float_as_int(dm));
        }
    }
    // reduce this i's pair partials — only boundary i (others never written)
    const float* __restrict__ outb = ws + 4096;
    float sv = 0.f, nv = 0.f;
    bool b = (i < n) && read_mask(bm, ic, !badb);
    if (b) {
        float c0 = 0.f, a1 = 0.f, a2 = 0.f;
        #pragma unroll
        for (int k = 0; k < NJ; ++k) {
            c0 += outb[(size_t)k*n + i];
            a1 += outb[(size_t)(NJ + k)*n + i];
            a2 += outb[(size_t)(2*NJ + k)*n + i];
        }
        float safe_n = fmaxf(c0, 2.f);
        float var = (a2 - a1*a1/safe_n) / (safe_n - 1.f);
        if (c0 > 1.f) { sv = var; nv = 1.f; }
    }
    sv = wave_sum(sv); nv = wave_sum(nv);
    if (lane == 0) { atomicAdd(&bacc[2], sv); atomicAdd(&bacc[3], nv); }
    __syncthreads();

    // publish per-block row {sd,sd2,maxd,sv,nv} (device-scope), then ticket
    float* row = ws + 1024 + blockIdx.x*16;
    if (tid < 5) {
        float val = (tid == 2) ? __int_as_float(bmax)
                  : (tid < 2 ? bacc[tid] : bacc[tid - 1]);
        atomicExch((int*)&row[tid], __float_as_int(val));
    }
    if (tid == 0) {
        __threadfence();
        unsigned prev = atomicAdd((unsigned*)ws, 1u);
        if (prev % (unsigned)gridDim.x == (unsigned)gridDim.x - 1u) lastf = 1;
    }
    __syncthreads();
    if (!lastf) return;

    // last block: gather rows with atomic loads (distinct lines, parallel)
    if (tid < 4) bacc[tid] = 0.f;
    if (tid == 0) bmax = 0;
    __syncthreads();
    for (int t = tid; t < nbi*5; t += 256) {
        int r = t / 5, col = t % 5;
        int bits = atomicOr((int*)&ws[1024 + r*16 + col], 0);
        if (col == 2) atomicMax(&bmax, bits);
        else {
            int dst = (col < 2) ? col : col - 1;
            atomicAdd(&bacc[dst], __int_as_float(bits));
        }
    }
    __syncthreads();
    if (tid != 0) return;

    float sd = bacc[0], sd2 = bacc[1], svv = bacc[2], niv = bacc[3];
    float maxd = __int_as_float(bmax);
    float pv = ctr[4], gv = ctr[5], nbm = ctr[6];

    // ellipsoid shape loss: cov from raw moments (double), closed-form eigvals
    float el = 0.0f;
    if (nh >= 10.0f) {
        double nn  = (double)nh;
        double cxd = (double)ctr[0]/nn, cyd = (double)ctr[1]/nn, czd = (double)ctr[2]/nn;
        double axx = (double)ctr[7]/nn  - cxd*cxd;
        double axy = (double)ctr[8]/nn  - cxd*cyd;
        double axz = (double)ctr[9]/nn  - cxd*czd;
        double ayy = (double)ctr[10]/nn - cyd*cyd;
        double ayz = (double)ctr[11]/nn - cyd*czd;
        double azz = (double)ctr[12]/nn - czd*czd;
        double p1 = axy*axy + axz*axz + ayz*ayz;
        double q  = (axx + ayy + azz) / 3.0;
        double p2 = (axx-q)*(axx-q) + (ayy-q)*(ayy-q) + (azz-q)*(azz-q) + 2.0*p1;
        double e0, e2;
        if (p2 < 1e-300) { e0 = e2 = q; }
        else {
            double p = sqrt(p2 / 6.0);
            double bxx = (axx-q)/p, byy = (ayy-q)/p, bzz = (azz-q)/p;
            double bxy = axy/p, bxz = axz/p, byz = ayz/p;
            double detB = bxx*(byy*bzz - byz*byz) - bxy*(bxy*bzz - byz*bxz)
                        + bxz*(bxy*byz - byy*bxz);
            double r2 = fmin(1.0, fmax(-1.0, detB * 0.5));
            double phi = acos(r2) / 3.0;
            e2 = q + 2.0*p*cos(phi);                       // largest
            e0 = q + 2.0*p*cos(phi + 2.0943951023931953);  // smallest
        }
        double e1 = 3.0*q - e2 - e0;
        double ra = e1/(e2 + (double)EPSF) - 1.0;
        double rc = e0/(e2 + (double)EPSF) - 1.0;
        el = (float)(ra*ra + rc*rc);
    }
    // size consistency
    float diff = pv - gv;
    float vol = diff * diff;
    float rel = fabsf(diff) / (gv > 0.0f ? gv : 1.0f);
    float sc = (gv > 0.0f) ? vol + 0.5f*rel : vol;
    // surface smoothness
    float mean_var = svv / fmaxf(niv, 1.0f);
    float ss = ((nbm >= 5.0f) && (niv > 0.0f)) ? mean_var : 0.0f;
    // connectivity
    float conn = 0.0f;
    if (nh >= 5.0f) {
        float var = (sd2 - sd*sd/nh) / (nh - 1.0f);
        conn = var / (maxd + EPSF);
    }
    out[0] = el + sc + ss + conn;
}

extern "C" void kernel_launch(void* const* d_in, const int* in_sizes, int n_in,
                              void* d_out, int out_size, void* d_ws, size_t ws_size,
                              hipStream_t stream) {
    const float* points = (const float*)d_in[0];
    const float* segp   = (const float*)d_in[1];
    const void*  bmask  = d_in[2];
    const void*  hmask  = d_in[3];
    const void*  pmask  = d_in[4];
    const void*  gmask  = d_in[5];
    float* ws  = (float*)d_ws;
    float* out = (float*)d_out;
    int n = in_sizes[2];            // 8192
    int nbi = (n + 255) / 256;      // 32 (j-tiles & k_final blocks)
    int nsl = (n + 511) / 512;      // 16 (i-slabs)

    k_pairs<<<dim3(nsl, NJ), 256, 0, stream>>>(points, segp, bmask, hmask,
                                               pmask, gmask, ws, n, nbi);
    k_final<<<nbi, 256, 0, stream>>>(points, bmask, hmask, ws, out, n, nbi, nsl);
}

// Round 13
// 26.045 us; speedup vs baseline: 1.5801x; 1.5801x over previous
//
#include <hip/hip_runtime.h>

#define EPSF 1e-8f
#define R2C  0.0025f   // 0.05^2
#define NJ   32        // j-chunks (grid.y of K1)

// ---------------- ws float-index layout ----------------
// wsu[0]                 : ticket for k_final (ACCUMULATING across launches;
//                          "prev % grid == grid-1" fires exactly once per
//                          launch for any start value -> no reset needed)
// ws[64 + sl*16 + 0..12] : K1 prep rows (sl < nsl=16):
//                          {hx,hy,hz,nh,pv,gv,nb,hxx,hxy,hxz,hyy,hyz,hzz}
// ws[1024 + blk*16+0..4] : K2 rows {sd, sd2, maxd, sv, nv} (atomic publish/read)
// ws[4096 + ...]         : pair partials cnt[NJ][n], sx[NJ][n], sx2[NJ][n]
// total ~3.2 MB << ws_size. Every word K2 reads is written by K1/K2 this launch.
// R11 lesson: keep partial stores thread->own-i (coalesced, fully-written
// region); i-side compaction scatters stores and regressed 15us.

__device__ inline int read_mask(const void* p, int i, int isInt) {
    if (isInt) return ((const int*)p)[i] != 0;
    return ((const unsigned char*)p)[i] != 0;
}
__device__ inline float wave_sum(float v) {
    #pragma unroll
    for (int o = 32; o > 0; o >>= 1) v += __shfl_down(v, o, 64);
    return v;
}
__device__ inline float wave_max(float v) {
    #pragma unroll
    for (int o = 32; o > 0; o >>= 1) v = fmaxf(v, __shfl_down(v, o, 64));
    return v;
}

// K1: pair sweep with per-tile j-compaction (only boundary j can match),
// 2 i-rows/thread. grid (nsl, NJ). c==0 plane emits 13-wide moment rows.
__global__ __launch_bounds__(256, 4)
void k_pairs(const float* __restrict__ pts, const float* __restrict__ segp,
             const void* bm, const void* hm, const void* pm, const void* gm,
             float* __restrict__ ws, int n, int nbi) {
    __shared__ float4 t4[256];
    __shared__ float2 tv[256];
    __shared__ int bad[4];
    __shared__ int wc[4];
    __shared__ float pacc[13];
    int tid = threadIdx.x, lane = tid & 63, wv = tid >> 6;
    int bx = blockIdx.x, c = blockIdx.y;

    if (tid < 4) { bad[tid] = 0; wc[tid] = 0; }
    if (tid < 13) pacc[tid] = 0.f;
    __syncthreads();
    {   // mask layout detect: byte layout shows nonzero upper bytes in the
        // first 256 words unless the first 1024 bools are all false (p~2^-768)
        unsigned w0 = ((const unsigned*)bm)[tid & 255];
        if (w0 & 0xFFFFFF00u) atomicOr(&bad[0], 1);
        if (c == 0) {
            unsigned w1 = ((const unsigned*)hm)[tid & 255];
            unsigned w2 = ((const unsigned*)pm)[tid & 255];
            unsigned w3 = ((const unsigned*)gm)[tid & 255];
            if (w1 & 0xFFFFFF00u) atomicOr(&bad[1], 1);
            if (w2 & 0xFFFFFF00u) atomicOr(&bad[2], 1);
            if (w3 & 0xFFFFFF00u) atomicOr(&bad[3], 1);
        }
    }
    __syncthreads();

    // ---- two i-rows per thread ----
    int i0 = bx*512 + tid, i1 = i0 + 256;
    int ic0 = min(i0, n-1), ic1 = min(i1, n-1);
    bool a0 = i0 < n, a1 = i1 < n;
    float x0 = pts[3*ic0], y0 = pts[3*ic0+1], z0 = pts[3*ic0+2];
    float x1 = pts[3*ic1], y1 = pts[3*ic1+1], z1 = pts[3*ic1+2];
    int b0 = read_mask(bm, ic0, !bad[0]) && a0;
    int b1 = read_mask(bm, ic1, !bad[0]) && a1;
    // threshold trick: d2 < R2C  <=>  t < R2C - sq_i ; non-boundary i: never
    float thr0 = b0 ? R2C - (x0*x0 + y0*y0 + z0*z0) : -1e30f;
    float thr1 = b1 ? R2C - (x1*x1 + y1*y1 + z1*z1) : -1e30f;

    if (c == 0) {   // prep rows: counts + first AND raw second head moments
        int h0 = read_mask(hm, ic0, !bad[1]) && a0;
        int h1 = read_mask(hm, ic1, !bad[1]) && a1;
        int p0 = read_mask(pm, ic0, !bad[2]) && a0;
        int p1 = read_mask(pm, ic1, !bad[2]) && a1;
        int g0 = read_mask(gm, ic0, !bad[3]) && a0;
        int g1 = read_mask(gm, ic1, !bad[3]) && a1;
        float hf0 = h0 ? 1.f : 0.f, hf1 = h1 ? 1.f : 0.f;
        float vals[13] = {
            hf0*x0 + hf1*x1, hf0*y0 + hf1*y1, hf0*z0 + hf1*z1,
            hf0 + hf1, (float)(p0 + p1), (float)(g0 + g1), (float)(b0 + b1),
            hf0*x0*x0 + hf1*x1*x1, hf0*x0*y0 + hf1*x1*y1, hf0*x0*z0 + hf1*x1*z1,
            hf0*y0*y0 + hf1*y1*y1, hf0*y0*z0 + hf1*y1*z1, hf0*z0*z0 + hf1*z1*z1 };
        #pragma unroll
        for (int k = 0; k < 13; ++k) {
            float s = wave_sum(vals[k]);
            if (lane == 0) atomicAdd(&pacc[k], s);   // LDS atomic: on-CU, cheap
        }
        __syncthreads();
        if (tid < 13) ws[64 + bx*16 + tid] = pacc[tid];
    }

    // ---- j-tile staging with boundary compaction (deterministic order:
    //      wave-id-major, lane-order minor; same every launch/replay) ----
    {
        int j = c*256 + tid;
        int jc = min(j, n-1);
        bool jb = (j < n) && read_mask(bm, jc, !bad[0]);
        float xj = pts[3*jc], yj = pts[3*jc+1], zj = pts[3*jc+2];
        float v = segp[3*jc+2];
        float sqj = xj*xj + yj*yj + zj*zj;
        unsigned long long ball = __ballot(jb);
        int pre = __popcll(ball & ((1ull << lane) - 1ull));
        if (lane == 0) wc[wv] = __popcll(ball);
        __syncthreads();
        int base = 0;
        #pragma unroll
        for (int w = 0; w < 4; ++w) base += (w < wv) ? wc[w] : 0;
        if (jb) {
            int r = base + pre;
            t4[r] = make_float4(-2.f*xj, -2.f*yj, -2.f*zj, sqj);
            tv[r] = make_float2(v, v*v);
        }
    }
    __syncthreads();
    int JC = wc[0] + wc[1] + wc[2] + wc[3];   // boundary count in this tile

    float c0a = 0.f, s10 = 0.f, s20 = 0.f;
    float c1a = 0.f, s11 = 0.f, s21 = 0.f;
    #pragma unroll 4
    for (int k = 0; k < JC; ++k) {
        float4 pj = t4[k];
        float2 vv = tv[k];
        float t0 = fmaf(pj.x, x0, pj.w);
        t0 = fmaf(pj.y, y0, t0);
        t0 = fmaf(pj.z, z0, t0);
        float m0 = (t0 < thr0) ? 1.f : 0.f;
        c0a += m0;
        s10 = fmaf(m0, vv.x, s10);
        s20 = fmaf(m0, vv.y, s20);
        float t1 = fmaf(pj.x, x1, pj.w);
        t1 = fmaf(pj.y, y1, t1);
        t1 = fmaf(pj.z, z1, t1);
        float m1 = (t1 < thr1) ? 1.f : 0.f;
        c1a += m1;
        s11 = fmaf(m1, vv.x, s11);
        s21 = fmaf(m1, vv.y, s21);
    }
    float* __restrict__ outb = ws + 4096;
    if (a0) {
        outb[(size_t)c*n + i0]          = c0a;
        outb[(size_t)(NJ + c)*n + i0]   = s10;
        outb[(size_t)(2*NJ + c)*n + i0] = s20;
    }
    if (a1) {
        outb[(size_t)c*n + i1]          = c1a;
        outb[(size_t)(NJ + c)*n + i1]   = s11;
        outb[(size_t)(2*NJ + c)*n + i1] = s21;
    }
}

// K2: conn reductions + partial reduce + last-block assembly (cov from moments).
__global__ void k_final(const float* __restrict__ pts, const void* bm, const void* hm,
                        float* __restrict__ ws, float* __restrict__ out,
                        int n, int nbi, int nsl) {
    __shared__ int badb, badh, lastf, bmax;
    __shared__ float ctr[13];
    __shared__ float bacc[4];    // {sd, sd2, sv, nv}
    int tid = threadIdx.x, lane = tid & 63;
    if (tid == 0) { badb = 0; badh = 0; lastf = 0; bmax = 0; }
    if (tid < 4) bacc[tid] = 0.f;
    __syncthreads();
    unsigned wb = ((const unsigned*)bm)[tid & 255];
    unsigned wh = ((const unsigned*)hm)[tid & 255];
    if (wb & 0xFFFFFF00u) atomicOr(&badb, 1);
    if (wh & 0xFFFFFF00u) atomicOr(&badh, 1);

    // sum prep rows (nsl <= 64) -> counts, centroid, raw moments
    if (tid < 64) {
        float s[13] = {0,0,0,0,0,0,0,0,0,0,0,0,0};
        for (int r = tid; r < nsl; r += 64) {
            #pragma unroll
            for (int k = 0; k < 13; ++k) s[k] += ws[64 + r*16 + k];
        }
        #pragma unroll
        for (int k = 0; k < 13; ++k) {
            #pragma unroll
            for (int o = 32; o > 0; o >>= 1) s[k] += __shfl_down(s[k], o, 64);
        }
        if (tid == 0) {
            #pragma unroll
            for (int k = 0; k < 13; ++k) ctr[k] = s[k];
        }
    }
    __syncthreads();

    float nh = ctr[3];
    float inv = (nh > 0.f) ? 1.f/nh : 0.f;
    float cx = ctr[0]*inv, cy = ctr[1]*inv, cz = ctr[2]*inv;
    int i = blockIdx.x*256 + tid;
    int ic = min(i, n-1);
    float act = (i < n) ? 1.f : 0.f;
    float x = pts[3*ic], y = pts[3*ic+1], z = pts[3*ic+2];
    int h = read_mask(hm, ic, !badh);
    float m = (h ? 1.f : 0.f) * act;
    float dx = x-cx, dy = y-cy, dz = z-cz;
    float d = sqrtf(dx*dx + dy*dy + dz*dz);
    {
        float s0 = wave_sum(m*d);
        float s1 = wave_sum(m*d*d);
        float dm = wave_max(m > 0.f ? d : 0.f);
        if (lane == 0) {
            atomicAdd(&bacc[0], s0); atomicAdd(&bacc[1], s1);
            atomicMax(&bmax, __float_as_int(dm));
        }
    }
    // reduce this i's pair partials
    const float* __restrict__ outb = ws + 4096;
    float sv = 0.f, nv = 0.f;
    if (i < n) {
        float c0 = 0.f, a1 = 0.f, a2 = 0.f;
        #pragma unroll
        for (int k = 0; k < NJ; ++k) {
            c0 += outb[(size_t)k*n + i];
            a1 += outb[(size_t)(NJ + k)*n + i];
            a2 += outb[(size_t)(2*NJ + k)*n + i];
        }
        int b = read_mask(bm, i, !badb);
        float safe_n = fmaxf(c0, 2.f);
        float var = (a2 - a1*a1/safe_n) / (safe_n - 1.f);
        if (b && c0 > 1.f) { sv = var; nv = 1.f; }
    }
    sv = wave_sum(sv); nv = wave_sum(nv);
    if (lane == 0) { atomicAdd(&bacc[2], sv); atomicAdd(&bacc[3], nv); }
    __syncthreads();

    // publish per-block row {sd,sd2,maxd,sv,nv} (device-scope), then ticket
    float* row = ws + 1024 + blockIdx.x*16;
    if (tid < 5) {
        float val = (tid == 2) ? __int_as_float(bmax)
                  : (tid < 2 ? bacc[tid] : bacc[tid - 1]);
        atomicExch((int*)&row[tid], __float_as_int(val));
    }
    if (tid == 0) {
        __threadfence();
        unsigned prev = atomicAdd((unsigned*)ws, 1u);
        if (prev % (unsigned)gridDim.x == (unsigned)gridDim.x - 1u) lastf = 1;
    }
    __syncthreads();
    if (!lastf) return;

    // last block: gather rows with atomic loads (distinct lines, parallel)
    if (tid < 4) bacc[tid] = 0.f;
    if (tid == 0) bmax = 0;
    __syncthreads();
    for (int t = tid; t < nbi*5; t += 256) {
        int r = t / 5, col = t % 5;
        int bits = atomicOr((int*)&ws[1024 + r*16 + col], 0);
        if (col == 2) atomicMax(&bmax, bits);
        else {
            int dst = (col < 2) ? col : col - 1;
            atomicAdd(&bacc[dst], __int_as_float(bits));
        }
    }
    __syncthreads();
    if (tid != 0) return;

    float sd = bacc[0], sd2 = bacc[1], svv = bacc[2], niv = bacc[3];
    float maxd = __int_as_float(bmax);
    float pv = ctr[4], gv = ctr[5], nbm = ctr[6];

    // ellipsoid shape loss: cov from raw moments (double), closed-form eigvals
    float el = 0.0f;
    if (nh >= 10.0f) {
        double nn  = (double)nh;
        double cxd = (double)ctr[0]/nn, cyd = (double)ctr[1]/nn, czd = (double)ctr[2]/nn;
        double axx = (double)ctr[7]/nn  - cxd*cxd;
        double axy = (double)ctr[8]/nn  - cxd*cyd;
        double axz = (double)ctr[9]/nn  - cxd*czd;
        double ayy = (double)ctr[10]/nn - cyd*cyd;
        double ayz = (double)ctr[11]/nn - cyd*czd;
        double azz = (double)ctr[12]/nn - czd*czd;
        double p1 = axy*axy + axz*axz + ayz*ayz;
        double q  = (axx + ayy + azz) / 3.0;
        double p2 = (axx-q)*(axx-q) + (ayy-q)*(ayy-q) + (azz-q)*(azz-q) + 2.0*p1;
        double e0, e2;
        if (p2 < 1e-300) { e0 = e2 = q; }
        else {
            double p = sqrt(p2 / 6.0);
            double bxx = (axx-q)/p, byy = (ayy-q)/p, bzz = (azz-q)/p;
            double bxy = axy/p, bxz = axz/p, byz = ayz/p;
            double detB = bxx*(byy*bzz - byz*byz) - bxy*(bxy*bzz - byz*bxz)
                        + bxz*(bxy*byz - byy*bxz);
            double r2 = fmin(1.0, fmax(-1.0, detB * 0.5));
            double phi = acos(r2) / 3.0;
            e2 = q + 2.0*p*cos(phi);                       // largest
            e0 = q + 2.0*p*cos(phi + 2.0943951023931953);  // smallest
        }
        double e1 = 3.0*q - e2 - e0;
        double ra = e1/(e2 + (double)EPSF) - 1.0;
        double rc = e0/(e2 + (double)EPSF) - 1.0;
        el = (float)(ra*ra + rc*rc);
    }
    // size consistency
    float diff = pv - gv;
    float vol = diff * diff;
    float rel = fabsf(diff) / (gv > 0.0f ? gv : 1.0f);
    float sc = (gv > 0.0f) ? vol + 0.5f*rel : vol;
    // surface smoothness
    float mean_var = svv / fmaxf(niv, 1.0f);
    float ss = ((nbm >= 5.0f) && (niv > 0.0f)) ? mean_var : 0.0f;
    // connectivity
    float conn = 0.0f;
    if (nh >= 5.0f) {
        float var = (sd2 - sd*sd/nh) / (nh - 1.0f);
        conn = var / (maxd + EPSF);
    }
    out[0] = el + sc + ss + conn;
}

extern "C" void kernel_launch(void* const* d_in, const int* in_sizes, int n_in,
                              void* d_out, int out_size, void* d_ws, size_t ws_size,
                              hipStream_t stream) {
    const float* points = (const float*)d_in[0];
    const float* segp   = (const float*)d_in[1];
    const void*  bmask  = d_in[2];
    const void*  hmask  = d_in[3];
    const void*  pmask  = d_in[4];
    const void*  gmask  = d_in[5];
    float* ws  = (float*)d_ws;
    float* out = (float*)d_out;
    int n = in_sizes[2];            // 8192
    int nbi = (n + 255) / 256;      // 32 (j-tiles & k_final blocks)
    int nsl = (n + 511) / 512;      // 16 (i-slices, 2 rows/thread)

    k_pairs<<<dim3(nsl, NJ), 256, 0, stream>>>(points, segp, bmask, hmask,
                                               pmask, gmask, ws, n, nbi);
    k_final<<<nbi, 256, 0, stream>>>(points, bmask, hmask, ws, out, n, nbi, nsl);
}